// Round 8
// baseline (649.949 us; speedup 1.0000x reference)
//
#include <hip/hip_runtime.h>
#include <hip/hip_fp16.h>

#define F_IN 512
#define BKT_BITS 7                 // 128 nodes per bucket
#define NPB (1 << BKT_BITS)
#define NBMAX 1024
#define BWIN 5120                  // fixed bucket window: mean 4096 + 16 sigma
#define EPT 32                     // edges per thread in partition phase
#define EPW (256 * EPT)            // 8192 edges per WG-slice

// LDS union across phases: max member 60 KB -> 2 blocks/CU (LDS-bound).
union SU {
    struct {                        // phase 1: partition
        unsigned int staged[EPW];   // 32 KB
        unsigned short bkt[EPW];    // 16 KB
        int hist[NBMAX];            // 4 KB
        int sc[NBMAX];              // 4 KB
        int base[NBMAX];            // 4 KB
        int wsum[4];
    } p;
    struct {                        // phase 2: per-bucket CSR
        int sorted[BWIN];           // 20 KB
        int hist[NPB];
        int sc[NPB];
        int curs[NPB];
    } c;
    struct {                        // phase 3: gemm1 transpose-reduce
        float red[4][64 * 17];      // 17.4 KB
    } g;
};

// device-scope sense-reversing grid barrier (requires co-resident grid).
// __threadfence() on gfx950 = agent-scope fence -> L2 writeback / invalidate,
// giving cross-XCD visibility for the phase handoff.
__device__ __forceinline__ void gbar(int* cnt, int* gen, int nblk) {
    __syncthreads();
    if (threadIdx.x == 0) {
        __threadfence();            // release my phase's writes
        int g = __hip_atomic_load(gen, __ATOMIC_RELAXED, __HIP_MEMORY_SCOPE_AGENT);
        if (__hip_atomic_fetch_add(cnt, 1, __ATOMIC_RELAXED,
                                   __HIP_MEMORY_SCOPE_AGENT) == nblk - 1) {
            __hip_atomic_store(cnt, 0, __ATOMIC_RELAXED, __HIP_MEMORY_SCOPE_AGENT);
            __hip_atomic_store(gen, g + 1, __ATOMIC_RELEASE, __HIP_MEMORY_SCOPE_AGENT);
        } else {
            while (__hip_atomic_load(gen, __ATOMIC_RELAXED,
                                     __HIP_MEMORY_SCOPE_AGENT) == g)
                __builtin_amdgcn_s_sleep(8);
        }
        __threadfence();            // acquire other blocks' writes
    }
    __syncthreads();
}

__global__ __launch_bounds__(256, 2) void k_fused(
    const float* __restrict__ x, const int* __restrict__ ei,
    const float* __restrict__ W1, const float* __restrict__ b1,
    const float* __restrict__ W2, const float* __restrict__ b2,
    float2* __restrict__ out,
    float* __restrict__ dinv, int2* __restrict__ pd, int* __restrict__ cursor,
    int* __restrict__ bar, unsigned int* __restrict__ pairs,
    __half2* __restrict__ hs, __half2* __restrict__ hs2,
    int n, int E, int nb, int nslice)
{
    __shared__ SU sh;
    const int tid  = threadIdx.x;
    const int lane = tid & 63;
    const int gsz  = gridDim.x * 256;
    const int* row = ei;
    const int* col = ei + E;

    // ---------------- phase 1: partition edges into bucket windows ----------
    // cursor[] pre-zeroed by host memset; holds per-bucket fill COUNT.
    for (int s = blockIdx.x; s < nslice; s += gridDim.x) {
        int e0 = s * EPW;
        for (int i = tid; i < nb; i += 256) sh.p.hist[i] = 0;
        __syncthreads();

        int4 c4[EPT / 4];
        int rank[EPT];
        #pragma unroll
        for (int k = 0; k < EPT / 4; ++k) {
            int e = e0 + (tid + k * 256) * 4;
            if (e + 3 < E) {
                c4[k] = ((const int4*)col)[e >> 2];
            } else {
                c4[k].x = (e     < E) ? col[e]     : -1;
                c4[k].y = (e + 1 < E) ? col[e + 1] : -1;
                c4[k].z = (e + 2 < E) ? col[e + 2] : -1;
                c4[k].w = (e + 3 < E) ? col[e + 3] : -1;
            }
            const int* cc = (const int*)&c4[k];
            #pragma unroll
            for (int i = 0; i < 4; ++i)
                rank[4 * k + i] = (cc[i] >= 0)
                    ? atomicAdd(&sh.p.hist[cc[i] >> BKT_BITS], 1) : 0;
        }
        __syncthreads();

        // bulk global reservation + 2-barrier hierarchical scan
        int i0 = tid * 4;
        int h0 = (i0     < nb) ? sh.p.hist[i0]     : 0;
        int h1 = (i0 + 1 < nb) ? sh.p.hist[i0 + 1] : 0;
        int h2 = (i0 + 2 < nb) ? sh.p.hist[i0 + 2] : 0;
        int h3 = (i0 + 3 < nb) ? sh.p.hist[i0 + 3] : 0;
        sh.p.base[i0]     = h0 ? i0 * BWIN       + atomicAdd(&cursor[i0],     h0) : 0;
        sh.p.base[i0 + 1] = h1 ? (i0 + 1) * BWIN + atomicAdd(&cursor[i0 + 1], h1) : 0;
        sh.p.base[i0 + 2] = h2 ? (i0 + 2) * BWIN + atomicAdd(&cursor[i0 + 2], h2) : 0;
        sh.p.base[i0 + 3] = h3 ? (i0 + 3) * BWIN + atomicAdd(&cursor[i0 + 3], h3) : 0;
        int ssum = h0 + h1 + h2 + h3;
        int ws = ssum;
        #pragma unroll
        for (int off = 1; off < 64; off <<= 1) {
            int t = __shfl_up(ws, off);
            if (lane >= off) ws += t;
        }
        if (lane == 63) sh.p.wsum[tid >> 6] = ws;
        __syncthreads();
        int woff = 0;
        #pragma unroll
        for (int k = 0; k < 4; ++k) woff += (k < (tid >> 6)) ? sh.p.wsum[k] : 0;
        int excl = woff + ws - ssum;
        sh.p.sc[i0]     = excl + h0;
        sh.p.sc[i0 + 1] = excl + h0 + h1;
        sh.p.sc[i0 + 2] = excl + h0 + h1 + h2;
        sh.p.sc[i0 + 3] = excl + ssum;
        __syncthreads();

        // stage: group this slice's edges by bucket in LDS
        #pragma unroll
        for (int k = 0; k < EPT / 4; ++k) {
            int e = e0 + (tid + k * 256) * 4;
            int4 r4;
            if (e + 3 < E) {
                r4 = ((const int4*)row)[e >> 2];
            } else {
                r4.x = (e     < E) ? row[e]     : 0;
                r4.y = (e + 1 < E) ? row[e + 1] : 0;
                r4.z = (e + 2 < E) ? row[e + 2] : 0;
                r4.w = (e + 3 < E) ? row[e + 3] : 0;
            }
            const int* cc = (const int*)&c4[k];
            const int* rr = (const int*)&r4;
            #pragma unroll
            for (int i = 0; i < 4; ++i) {
                if (e + i >= E || cc[i] < 0) continue;
                int b = cc[i] >> BKT_BITS;
                int pos = (sh.p.sc[b] - sh.p.hist[b]) + rank[4 * k + i];
                sh.p.staged[pos] = ((unsigned int)rr[i] << BKT_BITS)
                                 | (unsigned int)(cc[i] & (NPB - 1));
                sh.p.bkt[pos] = (unsigned short)b;
            }
        }
        __syncthreads();

        // run-grouped write-out (ascending bucket order)
        int vcnt = sh.p.sc[nb - 1];
        for (int i = tid; i < vcnt; i += 256) {
            int b = sh.p.bkt[i];
            int gpos = sh.p.base[b] + (i - (sh.p.sc[b] - sh.p.hist[b]));
            if (gpos < (b + 1) * BWIN)          // overflow guard (never fires)
                pairs[gpos] = sh.p.staged[i];
        }
        __syncthreads();
    }
    gbar(bar, bar + 1, gridDim.x);

    // ---------------- phase 2: per-bucket CSR (in-place, coalesced WB) ------
    for (int b = blockIdx.x; b < nb; b += gridDim.x) {
        int n0 = b << BKT_BITS;
        int w0 = b * BWIN;
        int ec = min(cursor[b], BWIN);
        if (tid < NPB) sh.c.hist[tid] = 0;
        __syncthreads();
        for (int e4 = tid; e4 < BWIN / 4; e4 += 256) {
            uint4 p4 = ((const uint4*)(pairs + w0))[e4];
            int e = e4 * 4;
            const unsigned int* pp = (const unsigned int*)&p4;
            #pragma unroll
            for (int i = 0; i < 4; ++i)
                if (e + i < ec) atomicAdd(&sh.c.hist[pp[i] & (NPB - 1)], 1);
        }
        __syncthreads();
        if (tid < NPB) sh.c.sc[tid] = sh.c.hist[tid];
        __syncthreads();
        for (int off = 1; off < NPB; off <<= 1) {
            int t = (tid < NPB && tid >= off) ? sh.c.sc[tid - off] : 0;
            __syncthreads();
            if (tid < NPB) sh.c.sc[tid] += t;
            __syncthreads();
        }
        if (tid < NPB) {
            int st = sh.c.sc[tid] - sh.c.hist[tid];
            sh.c.curs[tid] = st;
            int node = n0 + tid;
            if (node < n) {
                pd[node] = make_int2(w0 + st, sh.c.hist[tid]);
                dinv[node] = rsqrtf((float)(sh.c.hist[tid] + 1));  // +1 self-loop
            }
        }
        __syncthreads();
        for (int e4 = tid; e4 < BWIN / 4; e4 += 256) {
            uint4 p4 = ((const uint4*)(pairs + w0))[e4];
            int e = e4 * 4;
            const unsigned int* pp = (const unsigned int*)&p4;
            #pragma unroll
            for (int i = 0; i < 4; ++i) {
                if (e + i < ec) {
                    unsigned int p = pp[i];
                    int pos = atomicAdd(&sh.c.curs[p & (NPB - 1)], 1);
                    sh.c.sorted[pos] = (int)(p >> BKT_BITS);
                }
            }
        }
        __syncthreads();
        for (int i = tid; i < ec; i += 256)
            ((int*)pairs)[w0 + i] = sh.c.sorted[i];
        __syncthreads();
    }
    gbar(bar, bar + 1, gridDim.x);

    // ---------------- phase 3: hs = (x @ W1) * dinv, f16 --------------------
    {
        const int wib = tid >> 6;
        float* rb = sh.g.red[wib];
        float w[128];
        #pragma unroll
        for (int i = 0; i < 32; ++i) {
            float4 t = ((const float4*)W1)[lane * 32 + i];
            w[4*i+0] = t.x; w[4*i+1] = t.y; w[4*i+2] = t.z; w[4*i+3] = t.w;
        }
        const int q  = lane >> 4;
        const int jj = lane & 15;
        const int nw = gridDim.x * 4;

        int node = blockIdx.x * 4 + wib;
        float4 a = {}, b = {};
        float di = 0.f;
        if (node < n) {
            const float4* xr = (const float4*)(x + (size_t)node * F_IN);
            a = xr[lane * 2];
            b = xr[lane * 2 + 1];
            di = dinv[node];
        }
        while (node < n) {
            int nxt = node + nw;
            float4 an = {}, bn = {};
            float dn = 0.f;
            if (nxt < n) {                       // prefetch next node
                const float4* xr = (const float4*)(x + (size_t)nxt * F_IN);
                an = xr[lane * 2];
                bn = xr[lane * 2 + 1];
                dn = dinv[nxt];
            }
            float xs[8] = {a.x, a.y, a.z, a.w, b.x, b.y, b.z, b.w};
            float p[16];
            #pragma unroll
            for (int j = 0; j < 16; ++j) p[j] = 0.f;
            #pragma unroll
            for (int i = 0; i < 8; ++i)
                #pragma unroll
                for (int j = 0; j < 16; ++j)
                    p[j] = fmaf(xs[i], w[i * 16 + j], p[j]);

            #pragma unroll
            for (int j = 0; j < 16; ++j) rb[lane * 17 + j] = p[j];
            __asm__ volatile("s_waitcnt lgkmcnt(0)" ::: "memory");
            float s = 0.f;
            #pragma unroll
            for (int i = 0; i < 16; ++i) s += rb[(q * 16 + i) * 17 + jj];
            s += __shfl_down(s, 32);
            s += __shfl_down(s, 16);

            float sv = s * di;
            float sn = __shfl_down(sv, 1);
            if (lane < 16 && (lane & 1) == 0) {
                __half2 hv = __halves2half2(__float2half(sv), __float2half(sn));
                hs[node * 8 + (lane >> 1)] = hv;
            }
            node = nxt; a = an; b = bn; di = dn;
        }
    }
    gbar(bar, bar + 1, gridDim.x);

    // ---------------- phase 4: gather layer-1 + fused gemm2 -----------------
    {
        const int* csr = (const int*)pairs;
        for (int it = blockIdx.x * 256 + tid; it < n * 8; it += gsz) {
            int node = it >> 3, j2 = it & 7;
            int2 p = pd[node];
            int e = p.x, s1 = p.x + p.y;
            float2 sum = __half22float2(hs[node * 8 + j2]);  // self-loop
            for (; e + 8 <= s1; e += 8) {
                int a0 = csr[e],   a1 = csr[e+1], a2 = csr[e+2], a3 = csr[e+3];
                int a4 = csr[e+4], a5 = csr[e+5], a6 = csr[e+6], a7 = csr[e+7];
                float2 v0 = __half22float2(hs[a0 * 8 + j2]);
                float2 v1 = __half22float2(hs[a1 * 8 + j2]);
                float2 v2 = __half22float2(hs[a2 * 8 + j2]);
                float2 v3 = __half22float2(hs[a3 * 8 + j2]);
                float2 v4 = __half22float2(hs[a4 * 8 + j2]);
                float2 v5 = __half22float2(hs[a5 * 8 + j2]);
                float2 v6 = __half22float2(hs[a6 * 8 + j2]);
                float2 v7 = __half22float2(hs[a7 * 8 + j2]);
                sum.x += ((v0.x+v1.x)+(v2.x+v3.x)) + ((v4.x+v5.x)+(v6.x+v7.x));
                sum.y += ((v0.y+v1.y)+(v2.y+v3.y)) + ((v4.y+v5.y)+(v6.y+v7.y));
            }
            for (; e < s1; ++e) {
                float2 v = __half22float2(hs[csr[e] * 8 + j2]);
                sum.x += v.x; sum.y += v.y;
            }
            float di = dinv[node];
            float2 b1v = ((const float2*)b1)[j2];
            float va = fmaxf(fmaf(sum.x, di, b1v.x), 0.f);
            float vb = fmaxf(fmaf(sum.y, di, b1v.y), 0.f);
            float ha = 0.f, hb = 0.f;
            #pragma unroll
            for (int k2 = 0; k2 < 8; ++k2) {
                float oa = __shfl(va, k2, 8);
                float ob = __shfl(vb, k2, 8);
                ha = fmaf(oa, W2[(2*k2)   * 16 + 2*j2],     ha);
                hb = fmaf(oa, W2[(2*k2)   * 16 + 2*j2 + 1], hb);
                ha = fmaf(ob, W2[(2*k2+1) * 16 + 2*j2],     ha);
                hb = fmaf(ob, W2[(2*k2+1) * 16 + 2*j2 + 1], hb);
            }
            hs2[node * 8 + j2] =
                __halves2half2(__float2half(ha * di), __float2half(hb * di));
        }
    }
    gbar(bar, bar + 1, gridDim.x);

    // ---------------- phase 5: gather layer-2 + bias + log_softmax ----------
    {
        const int* csr = (const int*)pairs;
        for (int it = blockIdx.x * 256 + tid; it < n * 8; it += gsz) {
            int node = it >> 3, j2 = it & 7;
            int2 p = pd[node];
            int e = p.x, s1 = p.x + p.y;
            float2 sum = __half22float2(hs2[node * 8 + j2]); // self-loop
            for (; e + 8 <= s1; e += 8) {
                int a0 = csr[e],   a1 = csr[e+1], a2 = csr[e+2], a3 = csr[e+3];
                int a4 = csr[e+4], a5 = csr[e+5], a6 = csr[e+6], a7 = csr[e+7];
                float2 v0 = __half22float2(hs2[a0 * 8 + j2]);
                float2 v1 = __half22float2(hs2[a1 * 8 + j2]);
                float2 v2 = __half22float2(hs2[a2 * 8 + j2]);
                float2 v3 = __half22float2(hs2[a3 * 8 + j2]);
                float2 v4 = __half22float2(hs2[a4 * 8 + j2]);
                float2 v5 = __half22float2(hs2[a5 * 8 + j2]);
                float2 v6 = __half22float2(hs2[a6 * 8 + j2]);
                float2 v7 = __half22float2(hs2[a7 * 8 + j2]);
                sum.x += ((v0.x+v1.x)+(v2.x+v3.x)) + ((v4.x+v5.x)+(v6.x+v7.x));
                sum.y += ((v0.y+v1.y)+(v2.y+v3.y)) + ((v4.y+v5.y)+(v6.y+v7.y));
            }
            for (; e < s1; ++e) {
                float2 v = __half22float2(hs2[csr[e] * 8 + j2]);
                sum.x += v.x; sum.y += v.y;
            }
            float di = dinv[node];
            float2 b2v = ((const float2*)b2)[j2];
            float vx = fmaf(sum.x, di, b2v.x);
            float vy = fmaf(sum.y, di, b2v.y);
            float m = fmaxf(vx, vy);
            #pragma unroll
            for (int off = 4; off >= 1; off >>= 1) m = fmaxf(m, __shfl_xor(m, off));
            float s = expf(vx - m) + expf(vy - m);
            #pragma unroll
            for (int off = 4; off >= 1; off >>= 1) s += __shfl_xor(s, off);
            float ls = logf(s);
            out[node * 8 + j2] = make_float2(vx - m - ls, vy - m - ls);
        }
    }
}

extern "C" void kernel_launch(void* const* d_in, const int* in_sizes, int n_in,
                              void* d_out, int out_size, void* d_ws, size_t ws_size,
                              hipStream_t stream)
{
    const float* x  = (const float*)d_in[0];
    const int*   ei = (const int*)d_in[1];   // [2, E]: row then col
    const float* W1 = (const float*)d_in[2];
    const float* b1 = (const float*)d_in[3];
    const float* W2 = (const float*)d_in[4];
    const float* b2 = (const float*)d_in[5];
    float* out = (float*)d_out;

    const int n = in_sizes[0] / F_IN;            // 100000
    const int E = in_sizes[1] / 2;               // 3.2M
    const int nb = (n + NPB - 1) >> BKT_BITS;    // 782
    const int nslice = (E + EPW - 1) / EPW;      // 391

    // workspace: dinv | pd | cursor (NBMAX i32) | bar (512B) | pairs | hs | hs2
    char* ws = (char*)d_ws;
    size_t o = 0;
    #define ALIGN512(s) (((s) + 511) & ~(size_t)511)
    float* dinv = (float*)(ws + o);           o += ALIGN512((size_t)n * 4);
    int2*  pd   = (int2*)(ws + o);            o += ALIGN512((size_t)n * 8);
    int*   curs = (int*)(ws + o);             o += ALIGN512((size_t)NBMAX * 4);
    int*   bar  = (int*)(ws + o);             o += 512;
    unsigned int* pairs = (unsigned int*)(ws + o);
    o += ALIGN512((size_t)nb * BWIN * 4);
    __half2* hs  = (__half2*)(ws + o);        o += ALIGN512((size_t)n * 16 * 2);
    __half2* hs2 = (__half2*)(ws + o);        o += ALIGN512((size_t)n * 16 * 2);
    #undef ALIGN512

    // co-residency-safe grid size (cached; host-only queries, capture-safe)
    static int g_grid = 0;
    if (g_grid == 0) {
        int occ = 0;
        hipOccupancyMaxActiveBlocksPerMultiprocessor(&occ, k_fused, 256, 0);
        int ncu = 0;
        hipDeviceGetAttribute(&ncu, hipDeviceAttributeMultiprocessorCount, 0);
        if (occ < 1) occ = 1;
        if (ncu < 1) ncu = 256;
        g_grid = occ * ncu;
        if (g_grid > 2048) g_grid = 2048;
    }

    // zero cursor (4 KB) + barrier vars (adjacent 512 B) in one memset
    hipMemsetAsync(curs, 0, (size_t)NBMAX * 4 + 512, stream);
    k_fused<<<g_grid, 256, 0, stream>>>(x, ei, W1, b1, W2, b2, (float2*)out,
                                        dinv, pd, curs, bar, pairs, hs, hs2,
                                        n, E, nb, nslice);
}

// Round 9
// 577.766 us; speedup vs baseline: 1.1249x; 1.1249x over previous
//
#include <hip/hip_runtime.h>
#include <hip/hip_fp16.h>

#define F_IN 512
#define BKT_BITS 7                 // 128 nodes per bucket
#define NPB (1 << BKT_BITS)
#define NBMAX 1024
#define BWIN 5120                  // fixed bucket window: mean 4096 + 16 sigma
#define EPT 32                     // edges per thread in k_part
#define EPW (256 * EPT)            // 8192 edges per WG

// --- seed per-bucket cursors to window starts ---
__global__ void k_init(int* __restrict__ cursor, int nb) {
    int i = blockIdx.x * blockDim.x + threadIdx.x;
    if (i < nb) cursor[i] = i * BWIN;
}

// --- partition edges into fixed dst-bucket windows, LDS-sorted first (r7) ---
__global__ __launch_bounds__(256) void k_part(
    const int* __restrict__ row, const int* __restrict__ col,
    int* __restrict__ cursor, unsigned int* __restrict__ pairs, int E, int nb)
{
    __shared__ unsigned int staged[EPW];        // 32 KB
    __shared__ unsigned short bkt[EPW];         // 16 KB
    __shared__ int hist[NBMAX];                 // 4 KB
    __shared__ int sc[NBMAX];                   // 4 KB (inclusive scan)
    __shared__ int base[NBMAX];                 // 4 KB
    __shared__ int wsum[4];
    int tid = threadIdx.x;
    int lane = tid & 63;
    int e0 = blockIdx.x * EPW;
    for (int i = tid; i < nb; i += 256) hist[i] = 0;
    __syncthreads();

    int4 c4[EPT / 4];
    int rank[EPT];
    #pragma unroll
    for (int k = 0; k < EPT / 4; ++k) {
        int e = e0 + (tid + k * 256) * 4;
        if (e + 3 < E) {
            c4[k] = ((const int4*)col)[e >> 2];
        } else {
            c4[k].x = (e     < E) ? col[e]     : -1;
            c4[k].y = (e + 1 < E) ? col[e + 1] : -1;
            c4[k].z = (e + 2 < E) ? col[e + 2] : -1;
            c4[k].w = (e + 3 < E) ? col[e + 3] : -1;
        }
        const int* cc = (const int*)&c4[k];
        #pragma unroll
        for (int i = 0; i < 4; ++i)
            rank[4 * k + i] = (cc[i] >= 0) ? atomicAdd(&hist[cc[i] >> BKT_BITS], 1) : 0;
    }
    __syncthreads();

    // bulk global reservation per bucket + 2-barrier hierarchical scan
    int i0 = tid * 4;
    int h0 = (i0     < nb) ? hist[i0]     : 0;
    int h1 = (i0 + 1 < nb) ? hist[i0 + 1] : 0;
    int h2 = (i0 + 2 < nb) ? hist[i0 + 2] : 0;
    int h3 = (i0 + 3 < nb) ? hist[i0 + 3] : 0;
    base[i0]     = h0 ? atomicAdd(&cursor[i0],     h0) : 0;
    if (i0 + 1 < NBMAX) base[i0 + 1] = h1 ? atomicAdd(&cursor[i0 + 1], h1) : 0;
    if (i0 + 2 < NBMAX) base[i0 + 2] = h2 ? atomicAdd(&cursor[i0 + 2], h2) : 0;
    if (i0 + 3 < NBMAX) base[i0 + 3] = h3 ? atomicAdd(&cursor[i0 + 3], h3) : 0;
    int ssum = h0 + h1 + h2 + h3;
    int ws = ssum;
    #pragma unroll
    for (int off = 1; off < 64; off <<= 1) {
        int t = __shfl_up(ws, off);
        if (lane >= off) ws += t;
    }
    if (lane == 63) wsum[tid >> 6] = ws;
    __syncthreads();
    int woff = 0;
    #pragma unroll
    for (int k = 0; k < 4; ++k) woff += (k < (tid >> 6)) ? wsum[k] : 0;
    int excl = woff + ws - ssum;
    sc[i0]     = excl + h0;
    sc[i0 + 1] = excl + h0 + h1;
    sc[i0 + 2] = excl + h0 + h1 + h2;
    sc[i0 + 3] = excl + ssum;
    __syncthreads();

    // stage: group this WG's edges by bucket in LDS
    #pragma unroll
    for (int k = 0; k < EPT / 4; ++k) {
        int e = e0 + (tid + k * 256) * 4;
        int4 r4;
        if (e + 3 < E) {
            r4 = ((const int4*)row)[e >> 2];
        } else {
            r4.x = (e     < E) ? row[e]     : 0;
            r4.y = (e + 1 < E) ? row[e + 1] : 0;
            r4.z = (e + 2 < E) ? row[e + 2] : 0;
            r4.w = (e + 3 < E) ? row[e + 3] : 0;
        }
        const int* cc = (const int*)&c4[k];
        const int* rr = (const int*)&r4;
        #pragma unroll
        for (int i = 0; i < 4; ++i) {
            if (e + i >= E || cc[i] < 0) continue;
            int b = cc[i] >> BKT_BITS;
            int pos = (sc[b] - hist[b]) + rank[4 * k + i];   // local excl + rank
            staged[pos] = ((unsigned int)rr[i] << BKT_BITS)
                        | (unsigned int)(cc[i] & (NPB - 1));
            bkt[pos] = (unsigned short)b;
        }
    }
    __syncthreads();

    // run-grouped write-out (ascending bucket order -> few lines per store)
    int vcnt = sc[nb - 1];
    for (int i = tid; i < vcnt; i += 256) {
        int b = bkt[i];
        int gpos = base[b] + (i - (sc[b] - hist[b]));
        if (gpos < (b + 1) * BWIN)                  // overflow guard (never fires)
            pairs[gpos] = staged[i];
    }
}

// --- per-bucket exact CSR: hist+scan, LDS-sorted scatter, coalesced WB.
// Loops bounded by ec (not BWIN): kills the 25% window over-read, twice.
__global__ __launch_bounds__(256) void k_csr(
    unsigned int* __restrict__ pairs, const int* __restrict__ cursor,
    int2* __restrict__ pd, float* __restrict__ dinv, int n, int nb)
{
    __shared__ int sorted[BWIN];                    // 20 KB
    __shared__ int hist[NPB];
    __shared__ int sc[NPB];
    __shared__ int curs[NPB];
    int b = blockIdx.x, tid = threadIdx.x;
    int n0 = b << BKT_BITS;
    int w0 = b * BWIN;
    int ec = min(cursor[b] - w0, BWIN);
    int ec4 = (ec + 3) >> 2;
    if (tid < NPB) hist[tid] = 0;
    __syncthreads();
    // pass 1: histogram (vectorized, ec-bounded window read)
    for (int e4 = tid; e4 < ec4; e4 += 256) {
        uint4 p4 = ((const uint4*)(pairs + w0))[e4];
        int e = e4 * 4;
        const unsigned int* pp = (const unsigned int*)&p4;
        #pragma unroll
        for (int i = 0; i < 4; ++i)
            if (e + i < ec) atomicAdd(&hist[pp[i] & (NPB - 1)], 1);
    }
    __syncthreads();
    if (tid < NPB) sc[tid] = hist[tid];
    __syncthreads();
    for (int off = 1; off < NPB; off <<= 1) {
        int t = (tid < NPB && tid >= off) ? sc[tid - off] : 0;
        __syncthreads();
        if (tid < NPB) sc[tid] += t;
        __syncthreads();
    }
    if (tid < NPB) {
        int st = sc[tid] - hist[tid];               // exclusive start (local)
        curs[tid] = st;
        int node = n0 + tid;
        if (node < n) {
            pd[node] = make_int2(w0 + st, hist[tid]);
            dinv[node] = rsqrtf((float)(hist[tid] + 1));   // +1 self-loop
        }
    }
    __syncthreads();
    // pass 2: re-read window (L2-hot), scatter into LDS, not global
    for (int e4 = tid; e4 < ec4; e4 += 256) {
        uint4 p4 = ((const uint4*)(pairs + w0))[e4];
        int e = e4 * 4;
        const unsigned int* pp = (const unsigned int*)&p4;
        #pragma unroll
        for (int i = 0; i < 4; ++i) {
            if (e + i < ec) {
                unsigned int p = pp[i];
                int pos = atomicAdd(&curs[p & (NPB - 1)], 1);
                sorted[pos] = (int)(p >> BKT_BITS);
            }
        }
    }
    __syncthreads();
    // coalesced write-back
    for (int i = tid; i < ec; i += 256)
        ((int*)pairs)[w0 + i] = sorted[i];
}

// --- hs = (x @ W1) * dinv[node] f16. W1 held as 64 half2 VGPRs (was 128 f32)
// + __launch_bounds__(256,4): ~115 VGPR -> 4 waves/SIMD (was 2) -> 2x latency
// hiding on the dominant 205 MB x read. cvt overhead hides under memory.
__global__ __launch_bounds__(256, 4) void k_gemm1(
    const float* __restrict__ x, const float* __restrict__ W1,
    const float* __restrict__ dinv, __half2* __restrict__ hs, int n)
{
    __shared__ float red[4][64 * 17];
    const int lane = threadIdx.x & 63;
    const int wib  = threadIdx.x >> 6;
    const int wave = blockIdx.x * 4 + wib;
    const int nw   = gridDim.x * 4;
    float* rb = red[wib];

    __half2 w2[64];                  // W1 rows lane*8..lane*8+7, 16 cols, packed
    #pragma unroll
    for (int i = 0; i < 32; ++i) {
        float4 t = ((const float4*)W1)[lane * 32 + i];
        w2[2*i]   = __floats2half2_rn(t.x, t.y);
        w2[2*i+1] = __floats2half2_rn(t.z, t.w);
    }
    const int q  = lane >> 4;
    const int jj = lane & 15;

    int node = wave;
    float4 a = {}, b = {};
    float di = 0.f;
    if (node < n) {
        const float4* xr = (const float4*)(x + (size_t)node * F_IN);
        a = xr[lane * 2];
        b = xr[lane * 2 + 1];
        di = dinv[node];
    }
    while (node < n) {
        int nxt = node + nw;
        float4 an = {}, bn = {};
        float dn = 0.f;
        if (nxt < n) {                               // prefetch next node
            const float4* xr = (const float4*)(x + (size_t)nxt * F_IN);
            an = xr[lane * 2];
            bn = xr[lane * 2 + 1];
            dn = dinv[nxt];
        }
        float xs[8] = {a.x, a.y, a.z, a.w, b.x, b.y, b.z, b.w};
        float p[16];
        #pragma unroll
        for (int j = 0; j < 16; ++j) p[j] = 0.f;
        #pragma unroll
        for (int i = 0; i < 8; ++i) {
            #pragma unroll
            for (int jp = 0; jp < 8; ++jp) {
                float2 wv = __half22float2(w2[i * 8 + jp]);
                p[2*jp]   = fmaf(xs[i], wv.x, p[2*jp]);
                p[2*jp+1] = fmaf(xs[i], wv.y, p[2*jp+1]);
            }
        }

        #pragma unroll
        for (int j = 0; j < 16; ++j) rb[lane * 17 + j] = p[j];
        __asm__ volatile("s_waitcnt lgkmcnt(0)" ::: "memory");
        float s = 0.f;
        #pragma unroll
        for (int i = 0; i < 16; ++i) s += rb[(q * 16 + i) * 17 + jj];
        s += __shfl_down(s, 32);
        s += __shfl_down(s, 16);

        float sv = s * di;
        float sn = __shfl_down(sv, 1);
        if (lane < 16 && (lane & 1) == 0) {
            __half2 hv = __halves2half2(__float2half(sv), __float2half(sn));
            hs[node * 8 + (lane >> 1)] = hv;
        }
        node = nxt; a = an; b = bn; di = dn;
    }
}

// --- gather layer-1 + fused gemm2: 8 lanes/node, half2 loads (r5/r7-proven) ---
__global__ __launch_bounds__(256) void k_agg1(
    const __half2* __restrict__ hs, const int2* __restrict__ pd,
    const int* __restrict__ csr, const float* __restrict__ dinv,
    const float* __restrict__ b1, const float* __restrict__ W2,
    __half2* __restrict__ hs2, int n)
{
    int t = blockIdx.x * blockDim.x + threadIdx.x;
    int node = t >> 3, j2 = t & 7;                   // lane owns dims {2j2, 2j2+1}
    if (node >= n) return;
    int2 p = pd[node];
    int e = p.x, s1 = p.x + p.y;
    float2 sum = __half22float2(hs[node * 8 + j2]);  // self-loop
    for (; e + 8 <= s1; e += 8) {
        int a0 = csr[e],   a1 = csr[e+1], a2 = csr[e+2], a3 = csr[e+3];
        int a4 = csr[e+4], a5 = csr[e+5], a6 = csr[e+6], a7 = csr[e+7];
        float2 v0 = __half22float2(hs[a0 * 8 + j2]);
        float2 v1 = __half22float2(hs[a1 * 8 + j2]);
        float2 v2 = __half22float2(hs[a2 * 8 + j2]);
        float2 v3 = __half22float2(hs[a3 * 8 + j2]);
        float2 v4 = __half22float2(hs[a4 * 8 + j2]);
        float2 v5 = __half22float2(hs[a5 * 8 + j2]);
        float2 v6 = __half22float2(hs[a6 * 8 + j2]);
        float2 v7 = __half22float2(hs[a7 * 8 + j2]);
        sum.x += ((v0.x+v1.x)+(v2.x+v3.x)) + ((v4.x+v5.x)+(v6.x+v7.x));
        sum.y += ((v0.y+v1.y)+(v2.y+v3.y)) + ((v4.y+v5.y)+(v6.y+v7.y));
    }
    for (; e < s1; ++e) {
        float2 v = __half22float2(hs[csr[e] * 8 + j2]);
        sum.x += v.x; sum.y += v.y;
    }
    float di = dinv[node];
    float2 b1v = ((const float2*)b1)[j2];
    float va = fmaxf(fmaf(sum.x, di, b1v.x), 0.f);
    float vb = fmaxf(fmaf(sum.y, di, b1v.y), 0.f);
    float ha = 0.f, hb = 0.f;
    #pragma unroll
    for (int k2 = 0; k2 < 8; ++k2) {
        float oa = __shfl(va, k2, 8);                // v[2*k2]
        float ob = __shfl(vb, k2, 8);                // v[2*k2+1]
        ha = fmaf(oa, W2[(2*k2)   * 16 + 2*j2],     ha);
        hb = fmaf(oa, W2[(2*k2)   * 16 + 2*j2 + 1], hb);
        ha = fmaf(ob, W2[(2*k2+1) * 16 + 2*j2],     ha);
        hb = fmaf(ob, W2[(2*k2+1) * 16 + 2*j2 + 1], hb);
    }
    hs2[node * 8 + j2] = __halves2half2(__float2half(ha * di), __float2half(hb * di));
}

// --- gather layer-2 + fused bias + log_softmax: 8 lanes/node (r5/r7-proven) ---
__global__ __launch_bounds__(256) void k_agg2(
    const __half2* __restrict__ hs2, const int2* __restrict__ pd,
    const int* __restrict__ csr, const float* __restrict__ dinv,
    const float* __restrict__ b2, float2* __restrict__ out, int n)
{
    int t = blockIdx.x * blockDim.x + threadIdx.x;
    int node = t >> 3, j2 = t & 7;
    if (node >= n) return;
    int2 p = pd[node];
    int e = p.x, s1 = p.x + p.y;
    float2 sum = __half22float2(hs2[node * 8 + j2]); // self-loop
    for (; e + 8 <= s1; e += 8) {
        int a0 = csr[e],   a1 = csr[e+1], a2 = csr[e+2], a3 = csr[e+3];
        int a4 = csr[e+4], a5 = csr[e+5], a6 = csr[e+6], a7 = csr[e+7];
        float2 v0 = __half22float2(hs2[a0 * 8 + j2]);
        float2 v1 = __half22float2(hs2[a1 * 8 + j2]);
        float2 v2 = __half22float2(hs2[a2 * 8 + j2]);
        float2 v3 = __half22float2(hs2[a3 * 8 + j2]);
        float2 v4 = __half22float2(hs2[a4 * 8 + j2]);
        float2 v5 = __half22float2(hs2[a5 * 8 + j2]);
        float2 v6 = __half22float2(hs2[a6 * 8 + j2]);
        float2 v7 = __half22float2(hs2[a7 * 8 + j2]);
        sum.x += ((v0.x+v1.x)+(v2.x+v3.x)) + ((v4.x+v5.x)+(v6.x+v7.x));
        sum.y += ((v0.y+v1.y)+(v2.y+v3.y)) + ((v4.y+v5.y)+(v6.y+v7.y));
    }
    for (; e < s1; ++e) {
        float2 v = __half22float2(hs2[csr[e] * 8 + j2]);
        sum.x += v.x; sum.y += v.y;
    }
    float di = dinv[node];
    float2 b2v = ((const float2*)b2)[j2];
    float vx = fmaf(sum.x, di, b2v.x);
    float vy = fmaf(sum.y, di, b2v.y);
    float m = fmaxf(vx, vy);
    #pragma unroll
    for (int off = 4; off >= 1; off >>= 1) m = fmaxf(m, __shfl_xor(m, off));
    float s = expf(vx - m) + expf(vy - m);
    #pragma unroll
    for (int off = 4; off >= 1; off >>= 1) s += __shfl_xor(s, off);
    float ls = logf(s);
    out[node * 8 + j2] = make_float2(vx - m - ls, vy - m - ls);
}

extern "C" void kernel_launch(void* const* d_in, const int* in_sizes, int n_in,
                              void* d_out, int out_size, void* d_ws, size_t ws_size,
                              hipStream_t stream)
{
    const float* x  = (const float*)d_in[0];
    const int*   ei = (const int*)d_in[1];   // [2, E]: row then col
    const float* W1 = (const float*)d_in[2];
    const float* b1 = (const float*)d_in[3];
    const float* W2 = (const float*)d_in[4];
    const float* b2 = (const float*)d_in[5];
    float* out = (float*)d_out;

    const int n = in_sizes[0] / F_IN;            // 100000
    const int E = in_sizes[1] / 2;               // 3.2M
    const int nb = (n + NPB - 1) >> BKT_BITS;    // 782

    // workspace (~24 MB):
    // dinv (n f32) | pd (n int2) | cursor (1024 i32)
    // | pairs/csr (nb*BWIN u32, in-place) | hs (n*16 f16) | hs2 (n*16 f16)
    char* ws = (char*)d_ws;
    size_t o = 0;
    #define ALIGN512(s) (((s) + 511) & ~(size_t)511)
    float* dinv = (float*)(ws + o);           o += ALIGN512((size_t)n * 4);
    int2*  pd   = (int2*)(ws + o);            o += ALIGN512((size_t)n * 8);
    int*   curs = (int*)(ws + o);             o += ALIGN512((size_t)NBMAX * 4);
    unsigned int* pairs = (unsigned int*)(ws + o);
    o += ALIGN512((size_t)nb * BWIN * 4);
    __half2* hs  = (__half2*)(ws + o);        o += ALIGN512((size_t)n * 16 * 2);
    __half2* hs2 = (__half2*)(ws + o);        o += ALIGN512((size_t)n * 16 * 2);
    #undef ALIGN512

    k_init<<<(nb + 255) / 256, 256, 0, stream>>>(curs, nb);
    k_part<<<(E + EPW - 1) / EPW, 256, 0, stream>>>(ei, ei + E, curs, pairs, E, nb);
    k_csr <<<nb, 256, 0, stream>>>(pairs, curs, pd, dinv, n, nb);

    k_gemm1<<<2048, 256, 0, stream>>>(x, W1, dinv, hs, n);
    k_agg1 <<<(n * 8 + 255) / 256, 256, 0, stream>>>(hs, pd, (const int*)pairs,
                                                     dinv, b1, W2, hs2, n);
    k_agg2 <<<(n * 8 + 255) / 256, 256, 0, stream>>>(hs2, pd, (const int*)pairs,
                                                     dinv, b2, (float2*)out, n);
}

// Round 10
// 431.642 us; speedup vs baseline: 1.5058x; 1.3385x over previous
//
#include <hip/hip_runtime.h>
#include <hip/hip_fp16.h>

#define F_IN 512
#define BKT_BITS 7                 // 128 nodes per bucket
#define NPB (1 << BKT_BITS)
#define NBMAX 1024
#define BWIN 5120                  // fixed bucket window: mean 4096 + 16 sigma
#define EPT 32                     // edges per thread in k_part
#define EPW (256 * EPT)            // 8192 edges per WG

// --- seed per-bucket cursors to window starts ---
__global__ void k_init(int* __restrict__ cursor, int nb) {
    int i = blockIdx.x * blockDim.x + threadIdx.x;
    if (i < nb) cursor[i] = i * BWIN;
}

// --- partition edges into fixed dst-bucket windows, LDS-sorted first (r7) ---
__global__ __launch_bounds__(256) void k_part(
    const int* __restrict__ row, const int* __restrict__ col,
    int* __restrict__ cursor, unsigned int* __restrict__ pairs, int E, int nb)
{
    __shared__ unsigned int staged[EPW];        // 32 KB
    __shared__ unsigned short bkt[EPW];         // 16 KB
    __shared__ int hist[NBMAX];                 // 4 KB
    __shared__ int sc[NBMAX];                   // 4 KB (inclusive scan)
    __shared__ int base[NBMAX];                 // 4 KB
    __shared__ int wsum[4];
    int tid = threadIdx.x;
    int lane = tid & 63;
    int e0 = blockIdx.x * EPW;
    for (int i = tid; i < nb; i += 256) hist[i] = 0;
    __syncthreads();

    int4 c4[EPT / 4];
    int rank[EPT];
    #pragma unroll
    for (int k = 0; k < EPT / 4; ++k) {
        int e = e0 + (tid + k * 256) * 4;
        if (e + 3 < E) {
            c4[k] = ((const int4*)col)[e >> 2];
        } else {
            c4[k].x = (e     < E) ? col[e]     : -1;
            c4[k].y = (e + 1 < E) ? col[e + 1] : -1;
            c4[k].z = (e + 2 < E) ? col[e + 2] : -1;
            c4[k].w = (e + 3 < E) ? col[e + 3] : -1;
        }
        const int* cc = (const int*)&c4[k];
        #pragma unroll
        for (int i = 0; i < 4; ++i)
            rank[4 * k + i] = (cc[i] >= 0) ? atomicAdd(&hist[cc[i] >> BKT_BITS], 1) : 0;
    }
    __syncthreads();

    // bulk global reservation per bucket + 2-barrier hierarchical scan
    int i0 = tid * 4;
    int h0 = (i0     < nb) ? hist[i0]     : 0;
    int h1 = (i0 + 1 < nb) ? hist[i0 + 1] : 0;
    int h2 = (i0 + 2 < nb) ? hist[i0 + 2] : 0;
    int h3 = (i0 + 3 < nb) ? hist[i0 + 3] : 0;
    base[i0]     = h0 ? atomicAdd(&cursor[i0],     h0) : 0;
    if (i0 + 1 < NBMAX) base[i0 + 1] = h1 ? atomicAdd(&cursor[i0 + 1], h1) : 0;
    if (i0 + 2 < NBMAX) base[i0 + 2] = h2 ? atomicAdd(&cursor[i0 + 2], h2) : 0;
    if (i0 + 3 < NBMAX) base[i0 + 3] = h3 ? atomicAdd(&cursor[i0 + 3], h3) : 0;
    int ssum = h0 + h1 + h2 + h3;
    int ws = ssum;
    #pragma unroll
    for (int off = 1; off < 64; off <<= 1) {
        int t = __shfl_up(ws, off);
        if (lane >= off) ws += t;
    }
    if (lane == 63) wsum[tid >> 6] = ws;
    __syncthreads();
    int woff = 0;
    #pragma unroll
    for (int k = 0; k < 4; ++k) woff += (k < (tid >> 6)) ? wsum[k] : 0;
    int excl = woff + ws - ssum;
    sc[i0]     = excl + h0;
    sc[i0 + 1] = excl + h0 + h1;
    sc[i0 + 2] = excl + h0 + h1 + h2;
    sc[i0 + 3] = excl + ssum;
    __syncthreads();

    // stage: group this WG's edges by bucket in LDS
    #pragma unroll
    for (int k = 0; k < EPT / 4; ++k) {
        int e = e0 + (tid + k * 256) * 4;
        int4 r4;
        if (e + 3 < E) {
            r4 = ((const int4*)row)[e >> 2];
        } else {
            r4.x = (e     < E) ? row[e]     : 0;
            r4.y = (e + 1 < E) ? row[e + 1] : 0;
            r4.z = (e + 2 < E) ? row[e + 2] : 0;
            r4.w = (e + 3 < E) ? row[e + 3] : 0;
        }
        const int* cc = (const int*)&c4[k];
        const int* rr = (const int*)&r4;
        #pragma unroll
        for (int i = 0; i < 4; ++i) {
            if (e + i >= E || cc[i] < 0) continue;
            int b = cc[i] >> BKT_BITS;
            int pos = (sc[b] - hist[b]) + rank[4 * k + i];   // local excl + rank
            staged[pos] = ((unsigned int)rr[i] << BKT_BITS)
                        | (unsigned int)(cc[i] & (NPB - 1));
            bkt[pos] = (unsigned short)b;
        }
    }
    __syncthreads();

    // run-grouped write-out (ascending bucket order -> few lines per store)
    int vcnt = sc[nb - 1];
    for (int i = tid; i < vcnt; i += 256) {
        int b = bkt[i];
        int gpos = base[b] + (i - (sc[b] - hist[b]));
        if (gpos < (b + 1) * BWIN)                  // overflow guard (never fires)
            pairs[gpos] = staged[i];
    }
}

// --- per-bucket exact CSR: hist+scan, LDS-sorted scatter, coalesced WB (r9) ---
__global__ __launch_bounds__(256) void k_csr(
    unsigned int* __restrict__ pairs, const int* __restrict__ cursor,
    int2* __restrict__ pd, float* __restrict__ dinv, int n, int nb)
{
    __shared__ int sorted[BWIN];                    // 20 KB
    __shared__ int hist[NPB];
    __shared__ int sc[NPB];
    __shared__ int curs[NPB];
    int b = blockIdx.x, tid = threadIdx.x;
    int n0 = b << BKT_BITS;
    int w0 = b * BWIN;
    int ec = min(cursor[b] - w0, BWIN);
    int ec4 = (ec + 3) >> 2;
    if (tid < NPB) hist[tid] = 0;
    __syncthreads();
    for (int e4 = tid; e4 < ec4; e4 += 256) {
        uint4 p4 = ((const uint4*)(pairs + w0))[e4];
        int e = e4 * 4;
        const unsigned int* pp = (const unsigned int*)&p4;
        #pragma unroll
        for (int i = 0; i < 4; ++i)
            if (e + i < ec) atomicAdd(&hist[pp[i] & (NPB - 1)], 1);
    }
    __syncthreads();
    if (tid < NPB) sc[tid] = hist[tid];
    __syncthreads();
    for (int off = 1; off < NPB; off <<= 1) {
        int t = (tid < NPB && tid >= off) ? sc[tid - off] : 0;
        __syncthreads();
        if (tid < NPB) sc[tid] += t;
        __syncthreads();
    }
    if (tid < NPB) {
        int st = sc[tid] - hist[tid];               // exclusive start (local)
        curs[tid] = st;
        int node = n0 + tid;
        if (node < n) {
            pd[node] = make_int2(w0 + st, hist[tid]);
            dinv[node] = rsqrtf((float)(hist[tid] + 1));   // +1 self-loop
        }
    }
    __syncthreads();
    for (int e4 = tid; e4 < ec4; e4 += 256) {
        uint4 p4 = ((const uint4*)(pairs + w0))[e4];
        int e = e4 * 4;
        const unsigned int* pp = (const unsigned int*)&p4;
        #pragma unroll
        for (int i = 0; i < 4; ++i) {
            if (e + i < ec) {
                unsigned int p = pp[i];
                int pos = atomicAdd(&curs[p & (NPB - 1)], 1);
                sorted[pos] = (int)(p >> BKT_BITS);
            }
        }
    }
    __syncthreads();
    for (int i = tid; i < ec; i += 256)
        ((int*)pairs)[w0 + i] = sorted[i];
}

// --- hs = (x @ W1) * dinv, f16. TWO WAVES per node: each lane holds only
// 4 W1 rows (w[64] f32, ~105 VGPR -> 4 waves/SIMD, no spill risk) and loads
// one float4 of x. Cross-wave reduce via 16-float LDS exchange. Doubles
// latency hiding on the dominant 205 MB x stream vs r7's 2 waves/SIMD.
__global__ __launch_bounds__(256) void k_gemm1(
    const float* __restrict__ x, const float* __restrict__ W1,
    const float* __restrict__ dinv, __half2* __restrict__ hs, int n)
{
    __shared__ float red[2][128 * 17];              // 17.4 KB, pad 17
    __shared__ float red2[2][16];
    const int tid  = threadIdx.x;
    const int lane = tid & 63;
    const int pairIdx = tid >> 7;                   // which node of the pair
    const int ln   = tid & 127;                     // lane within node
    const int wv   = (tid >> 6) & 1;                // wave within node
    float* rb = red[pairIdx];

    float w[64];                                    // rows ln*4..ln*4+3, 16 cols
    #pragma unroll
    for (int i = 0; i < 16; ++i) {
        float4 t = ((const float4*)W1)[ln * 16 + i];
        int rr = i >> 2, c0 = (i & 3) * 4;
        w[rr * 16 + c0 + 0] = t.x;
        w[rr * 16 + c0 + 1] = t.y;
        w[rr * 16 + c0 + 2] = t.z;
        w[rr * 16 + c0 + 3] = t.w;
    }

    const int stride = gridDim.x * 2;
    int base = blockIdx.x * 2;
    int node = base + pairIdx;
    bool act = node < n;
    float4 a = {};
    float di = 0.f;
    if (act) {
        a = ((const float4*)(x + (size_t)node * F_IN))[ln];
        if (wv == 0) di = dinv[node];
    }
    while (base < n) {                              // block-uniform condition
        int nbase = base + stride;
        int nxt = nbase + pairIdx;
        float4 an = {};
        float dn = 0.f;
        if (nxt < n) {                              // prefetch next node
            an = ((const float4*)(x + (size_t)nxt * F_IN))[ln];
            if (wv == 0) dn = dinv[nxt];
        }
        float xs[4] = {a.x, a.y, a.z, a.w};
        float p[16];
        #pragma unroll
        for (int j = 0; j < 16; ++j) p[j] = 0.f;
        #pragma unroll
        for (int rr = 0; rr < 4; ++rr)
            #pragma unroll
            for (int j = 0; j < 16; ++j)
                p[j] = fmaf(xs[rr], w[rr * 16 + j], p[j]);

        #pragma unroll
        for (int j = 0; j < 16; ++j) rb[ln * 17 + j] = p[j];
        __syncthreads();
        int jj = ln & 15, chunk = ln >> 4;
        float s = 0.f;
        #pragma unroll
        for (int t = 0; t < 16; ++t) s += rb[(chunk * 16 + t) * 17 + jj];
        s += __shfl_down(s, 32);
        s += __shfl_down(s, 16);
        if (wv == 1 && lane < 16) red2[pairIdx][lane] = s;
        __syncthreads();
        if (wv == 0) {
            if (lane < 16) s += red2[pairIdx][lane];
            float sv = s * di;
            float sn = __shfl_down(sv, 1);
            if (act && lane < 16 && (lane & 1) == 0) {
                __half2 hv = __halves2half2(__float2half(sv), __float2half(sn));
                hs[node * 8 + (lane >> 1)] = hv;
            }
        }
        base = nbase; node = nxt; act = node < n; a = an; di = dn;
    }
}

// --- gather layer-1 + fused gemm2: 8 lanes/node, half2 loads (r5/r7-proven) ---
__global__ __launch_bounds__(256) void k_agg1(
    const __half2* __restrict__ hs, const int2* __restrict__ pd,
    const int* __restrict__ csr, const float* __restrict__ dinv,
    const float* __restrict__ b1, const float* __restrict__ W2,
    __half2* __restrict__ hs2, int n)
{
    int t = blockIdx.x * blockDim.x + threadIdx.x;
    int node = t >> 3, j2 = t & 7;                   // lane owns dims {2j2, 2j2+1}
    if (node >= n) return;
    int2 p = pd[node];
    int e = p.x, s1 = p.x + p.y;
    float2 sum = __half22float2(hs[node * 8 + j2]);  // self-loop
    for (; e + 8 <= s1; e += 8) {
        int a0 = csr[e],   a1 = csr[e+1], a2 = csr[e+2], a3 = csr[e+3];
        int a4 = csr[e+4], a5 = csr[e+5], a6 = csr[e+6], a7 = csr[e+7];
        float2 v0 = __half22float2(hs[a0 * 8 + j2]);
        float2 v1 = __half22float2(hs[a1 * 8 + j2]);
        float2 v2 = __half22float2(hs[a2 * 8 + j2]);
        float2 v3 = __half22float2(hs[a3 * 8 + j2]);
        float2 v4 = __half22float2(hs[a4 * 8 + j2]);
        float2 v5 = __half22float2(hs[a5 * 8 + j2]);
        float2 v6 = __half22float2(hs[a6 * 8 + j2]);
        float2 v7 = __half22float2(hs[a7 * 8 + j2]);
        sum.x += ((v0.x+v1.x)+(v2.x+v3.x)) + ((v4.x+v5.x)+(v6.x+v7.x));
        sum.y += ((v0.y+v1.y)+(v2.y+v3.y)) + ((v4.y+v5.y)+(v6.y+v7.y));
    }
    for (; e < s1; ++e) {
        float2 v = __half22float2(hs[csr[e] * 8 + j2]);
        sum.x += v.x; sum.y += v.y;
    }
    float di = dinv[node];
    float2 b1v = ((const float2*)b1)[j2];
    float va = fmaxf(fmaf(sum.x, di, b1v.x), 0.f);
    float vb = fmaxf(fmaf(sum.y, di, b1v.y), 0.f);
    float ha = 0.f, hb = 0.f;
    #pragma unroll
    for (int k2 = 0; k2 < 8; ++k2) {
        float oa = __shfl(va, k2, 8);                // v[2*k2]
        float ob = __shfl(vb, k2, 8);                // v[2*k2+1]
        ha = fmaf(oa, W2[(2*k2)   * 16 + 2*j2],     ha);
        hb = fmaf(oa, W2[(2*k2)   * 16 + 2*j2 + 1], hb);
        ha = fmaf(ob, W2[(2*k2+1) * 16 + 2*j2],     ha);
        hb = fmaf(ob, W2[(2*k2+1) * 16 + 2*j2 + 1], hb);
    }
    hs2[node * 8 + j2] = __halves2half2(__float2half(ha * di), __float2half(hb * di));
}

// --- gather layer-2 + fused bias + log_softmax: 8 lanes/node (r5/r7-proven) ---
__global__ __launch_bounds__(256) void k_agg2(
    const __half2* __restrict__ hs2, const int2* __restrict__ pd,
    const int* __restrict__ csr, const float* __restrict__ dinv,
    const float* __restrict__ b2, float2* __restrict__ out, int n)
{
    int t = blockIdx.x * blockDim.x + threadIdx.x;
    int node = t >> 3, j2 = t & 7;
    if (node >= n) return;
    int2 p = pd[node];
    int e = p.x, s1 = p.x + p.y;
    float2 sum = __half22float2(hs2[node * 8 + j2]); // self-loop
    for (; e + 8 <= s1; e += 8) {
        int a0 = csr[e],   a1 = csr[e+1], a2 = csr[e+2], a3 = csr[e+3];
        int a4 = csr[e+4], a5 = csr[e+5], a6 = csr[e+6], a7 = csr[e+7];
        float2 v0 = __half22float2(hs2[a0 * 8 + j2]);
        float2 v1 = __half22float2(hs2[a1 * 8 + j2]);
        float2 v2 = __half22float2(hs2[a2 * 8 + j2]);
        float2 v3 = __half22float2(hs2[a3 * 8 + j2]);
        float2 v4 = __half22float2(hs2[a4 * 8 + j2]);
        float2 v5 = __half22float2(hs2[a5 * 8 + j2]);
        float2 v6 = __half22float2(hs2[a6 * 8 + j2]);
        float2 v7 = __half22float2(hs2[a7 * 8 + j2]);
        sum.x += ((v0.x+v1.x)+(v2.x+v3.x)) + ((v4.x+v5.x)+(v6.x+v7.x));
        sum.y += ((v0.y+v1.y)+(v2.y+v3.y)) + ((v4.y+v5.y)+(v6.y+v7.y));
    }
    for (; e < s1; ++e) {
        float2 v = __half22float2(hs2[csr[e] * 8 + j2]);
        sum.x += v.x; sum.y += v.y;
    }
    float di = dinv[node];
    float2 b2v = ((const float2*)b2)[j2];
    float vx = fmaf(sum.x, di, b2v.x);
    float vy = fmaf(sum.y, di, b2v.y);
    float m = fmaxf(vx, vy);
    #pragma unroll
    for (int off = 4; off >= 1; off >>= 1) m = fmaxf(m, __shfl_xor(m, off));
    float s = expf(vx - m) + expf(vy - m);
    #pragma unroll
    for (int off = 4; off >= 1; off >>= 1) s += __shfl_xor(s, off);
    float ls = logf(s);
    out[node * 8 + j2] = make_float2(vx - m - ls, vy - m - ls);
}

extern "C" void kernel_launch(void* const* d_in, const int* in_sizes, int n_in,
                              void* d_out, int out_size, void* d_ws, size_t ws_size,
                              hipStream_t stream)
{
    const float* x  = (const float*)d_in[0];
    const int*   ei = (const int*)d_in[1];   // [2, E]: row then col
    const float* W1 = (const float*)d_in[2];
    const float* b1 = (const float*)d_in[3];
    const float* W2 = (const float*)d_in[4];
    const float* b2 = (const float*)d_in[5];
    float* out = (float*)d_out;

    const int n = in_sizes[0] / F_IN;            // 100000
    const int E = in_sizes[1] / 2;               // 3.2M
    const int nb = (n + NPB - 1) >> BKT_BITS;    // 782

    // workspace (~24 MB):
    // dinv (n f32) | pd (n int2) | cursor (1024 i32)
    // | pairs/csr (nb*BWIN u32, in-place) | hs (n*16 f16) | hs2 (n*16 f16)
    char* ws = (char*)d_ws;
    size_t o = 0;
    #define ALIGN512(s) (((s) + 511) & ~(size_t)511)
    float* dinv = (float*)(ws + o);           o += ALIGN512((size_t)n * 4);
    int2*  pd   = (int2*)(ws + o);            o += ALIGN512((size_t)n * 8);
    int*   curs = (int*)(ws + o);             o += ALIGN512((size_t)NBMAX * 4);
    unsigned int* pairs = (unsigned int*)(ws + o);
    o += ALIGN512((size_t)nb * BWIN * 4);
    __half2* hs  = (__half2*)(ws + o);        o += ALIGN512((size_t)n * 16 * 2);
    __half2* hs2 = (__half2*)(ws + o);        o += ALIGN512((size_t)n * 16 * 2);
    #undef ALIGN512

    k_init<<<(nb + 255) / 256, 256, 0, stream>>>(curs, nb);
    k_part<<<(E + EPW - 1) / EPW, 256, 0, stream>>>(ei, ei + E, curs, pairs, E, nb);
    k_csr <<<nb, 256, 0, stream>>>(pairs, curs, pd, dinv, n, nb);

    k_gemm1<<<2048, 256, 0, stream>>>(x, W1, dinv, hs, n);
    k_agg1 <<<(n * 8 + 255) / 256, 256, 0, stream>>>(hs, pd, (const int*)pairs,
                                                     dinv, b1, W2, hs2, n);
    k_agg2 <<<(n * 8 + 255) / 256, 256, 0, stream>>>(hs2, pd, (const int*)pairs,
                                                     dinv, b2, (float2*)out, n);
}